// Round 7
// baseline (15546.529 us; speedup 1.0000x reference)
//
#include <hip/hip_runtime.h>
#include <hip/hip_fp16.h>
#include <math.h>

#define NSTEPS 512
#define BATCH  256
#define NIN    64
#define NN     256

__device__ __forceinline__ float2 h2f(uint32_t u) {
    __half2 h; *(uint32_t*)&h = u; return __half22float2(h);
}

// butterfly-add within 16-lane DPP row; CTRL: 0xB1=xor1, 0x4E=xor2,
// 0x141=row_half_mirror (xor7 pairing), 0x128=row_ror:8 (xor8 within 16)
template<int CTRL>
__device__ __forceinline__ float dpp_add(float v) {
    int p = __builtin_amdgcn_update_dpp(0, __float_as_int(v), CTRL, 0xF, 0xF, true);
    return v + __int_as_float(p);
}

// ===========================================================================
// Phase 0: pack Wc_ih / Wc_hh transposed + k-quad-packed fp16:
//   W4T[(m*64 + kq)*256 + n] = half4{ Wc_m[n][4kq..4kq+3] }
// ===========================================================================
extern "C" __global__ void pack_kernel(const float* __restrict__ Wc_ih,
                                       const float* __restrict__ Wc_hh,
                                       uint2* __restrict__ W4T)
{
    const int n = blockIdx.x, t = threadIdx.x;
    {
        float4 v = ((const float4*)(Wc_ih + n * NN))[t];
        __half2 a = __floats2half2_rn(v.x, v.y);
        __half2 c = __floats2half2_rn(v.z, v.w);
        uint2 o; o.x = *(uint32_t*)&a; o.y = *(uint32_t*)&c;
        W4T[t * 256 + n] = o;
    }
    {
        float4 v = ((const float4*)(Wc_hh + n * NN))[t];
        __half2 a = __floats2half2_rn(v.x, v.y);
        __half2 c = __floats2half2_rn(v.z, v.w);
        uint2 o; o.x = *(uint32_t*)&a; o.y = *(uint32_t*)&c;
        W4T[(64 + t) * 256 + n] = o;
    }
}

// ===========================================================================
// Phase 1: tanh RNN. 1024 threads, (n = t&255, kq = t>>8).
// __launch_bounds__(1024, 1): 1 block/CU, VGPR cap 128 -> 80-reg weight
// arrays stay in registers (prior (1024,4) risked a 64-reg cap -> spill).
// Writes A2 (B, S, N) fp16.
// ===========================================================================
extern "C" __global__ void __launch_bounds__(1024, 1)
rnn_kernel(const float* __restrict__ X, const float* __restrict__ W_ih,
           const float* __restrict__ W_hh, const float* __restrict__ b_ih,
           const float* __restrict__ b_hh, __half* __restrict__ A2)
{
    const int b = blockIdx.x, t = threadIdx.x;
    const int n = t & 255, kq = t >> 8;

    __shared__ float h_lds[NN];
    __shared__ float x_lds[NIN];
    __shared__ float part[4 * NN];

    float wih[16];
#pragma unroll
    for (int j = 0; j < 16; ++j) wih[j] = W_ih[n * NIN + kq * 16 + j];
    float whh[64];
#pragma unroll
    for (int j = 0; j < 64; ++j) whh[j] = W_hh[n * NN + kq * 64 + j];
    const float bias = b_ih[n] + b_hh[n];

    float xr = (t < NIN) ? X[b * NIN + t] : 0.f;
    if (t < NN) h_lds[t] = 0.f;
    __syncthreads();

    __half2* Ab2 = (__half2*)(A2 + (size_t)b * NSTEPS * NN);

    for (int s = 0; s < NSTEPS; ++s) {
        if (t < NIN) x_lds[t] = xr;
        __syncthreads();
        if (t < NIN && s + 1 < NSTEPS) xr = X[((s + 1) * BATCH + b) * NIN + t];

        float a0 = 0.f, a1 = 0.f;
#pragma unroll
        for (int j = 0; j < 16; ++j) a0 = fmaf(wih[j], x_lds[kq * 16 + j], a0);
#pragma unroll
        for (int j = 0; j < 64; ++j) a1 = fmaf(whh[j], h_lds[kq * 64 + j], a1);
        part[kq * NN + n] = a0 + a1;
        __syncthreads();
        if (t < NN) {
            const float hn = tanhf(part[t] + part[NN + t] + part[2 * NN + t] +
                                   part[3 * NN + t] + bias);
            h_lds[t] = hn;
            const float hn1 = __shfl_down(hn, 1);
            if (!(t & 1)) Ab2[s * (NN / 2) + (t >> 1)] = __floats2half2_rn(hn, hn1);
        }
        __syncthreads();
    }
}

// ===========================================================================
// Phase 2 v3.1: REGISTER-RESIDENT A, launch-bounds fixed.
// __launch_bounds__(512, 1): allocator may use up to 256 VGPRs (a 512-thread
// block needs 2 waves/SIMD -> hard cap 256, so 1 block/CU guaranteed).
// Lane (w, sr=lane>>4, nc=lane&15) holds A rows w*64+sr*16..+15, cols
// nc*16..+15 as 32 uint4 (128 VGPRs, now actually in registers).
// ===========================================================================
__device__ __forceinline__ float dot16(uint4 wa, uint4 wb, const float* hpr) {
    float a = 0.f; float2 f;
    f = h2f(wa.x); a = fmaf(f.x, hpr[0],  a); a = fmaf(f.y, hpr[1],  a);
    f = h2f(wa.y); a = fmaf(f.x, hpr[2],  a); a = fmaf(f.y, hpr[3],  a);
    f = h2f(wa.z); a = fmaf(f.x, hpr[4],  a); a = fmaf(f.y, hpr[5],  a);
    f = h2f(wa.w); a = fmaf(f.x, hpr[6],  a); a = fmaf(f.y, hpr[7],  a);
    f = h2f(wb.x); a = fmaf(f.x, hpr[8],  a); a = fmaf(f.y, hpr[9],  a);
    f = h2f(wb.y); a = fmaf(f.x, hpr[10], a); a = fmaf(f.y, hpr[11], a);
    f = h2f(wb.z); a = fmaf(f.x, hpr[12], a); a = fmaf(f.y, hpr[13], a);
    f = h2f(wb.w); a = fmaf(f.x, hpr[14], a); a = fmaf(f.y, hpr[15], a);
    return a;
}

__device__ __forceinline__ void axpy16(float e, uint4 wa, uint4 wb, float* ap) {
    float2 f;
    f = h2f(wa.x); ap[0]  = fmaf(e, f.x, ap[0]);  ap[1]  = fmaf(e, f.y, ap[1]);
    f = h2f(wa.y); ap[2]  = fmaf(e, f.x, ap[2]);  ap[3]  = fmaf(e, f.y, ap[3]);
    f = h2f(wa.z); ap[4]  = fmaf(e, f.x, ap[4]);  ap[5]  = fmaf(e, f.y, ap[5]);
    f = h2f(wa.w); ap[6]  = fmaf(e, f.x, ap[6]);  ap[7]  = fmaf(e, f.y, ap[7]);
    f = h2f(wb.x); ap[8]  = fmaf(e, f.x, ap[8]);  ap[9]  = fmaf(e, f.y, ap[9]);
    f = h2f(wb.y); ap[10] = fmaf(e, f.x, ap[10]); ap[11] = fmaf(e, f.y, ap[11]);
    f = h2f(wb.z); ap[12] = fmaf(e, f.x, ap[12]); ap[13] = fmaf(e, f.y, ap[13]);
    f = h2f(wb.w); ap[14] = fmaf(e, f.x, ap[14]); ap[15] = fmaf(e, f.y, ap[15]);
}

extern "C" __global__ void __launch_bounds__(512, 1)
attn_kernel(const __half* __restrict__ A2, const uint2* __restrict__ W4T,
            const float* __restrict__ bc_ih, const float* __restrict__ bc_hh,
            const float* __restrict__ W_fc, const float* __restrict__ b_fc,
            float* __restrict__ out)
{
    __shared__ float hp_pad[320];       // 16 groups x (16 data + 4 pad)
    __shared__ float at_pad[320];
    __shared__ float att_part[8 * 320]; // per-wave col partials, padded groups
    __shared__ float wred[8];
    __shared__ float wsum[8];
    __shared__ float mvih[256];

    const int b    = blockIdx.x;
    const int t    = threadIdx.x;
    const int lane = t & 63;
    const int w    = t >> 6;
    const int sr   = lane >> 4;
    const int nc   = lane & 15;
    const int un   = t & 255;
    const float bcs = bc_ih[un] + bc_hh[un];

    // ---- load A tile into registers (rows w*64+sr*16+i, cols nc*16..+15)
    uint4 areg[32];
    {
        const uint4* gA = (const uint4*)(A2 + (size_t)b * NSTEPS * NN);
        const int rbase = w * 64 + sr * 16;
#pragma unroll
        for (int i = 0; i < 16; ++i) {
            areg[2 * i]     = gA[(rbase + i) * 32 + nc * 2];
            areg[2 * i + 1] = gA[(rbase + i) * 32 + nc * 2 + 1];
        }
    }

    if (t < 256) hp_pad[(t >> 4) * 20 + (t & 15)] = 0.f;
    __syncthreads();

    float a_hh = 0.f;

    for (int it = 0; it < NN; ++it) {
        // ---- hp col slice (16 floats, padded groups, 2-way max)
        float hpr[16];
        {
            const float4* hq = (const float4*)&hp_pad[nc * 20];
#pragma unroll
            for (int k = 0; k < 4; ++k) {
                float4 v = hq[k];
                hpr[4*k] = v.x; hpr[4*k+1] = v.y; hpr[4*k+2] = v.z; hpr[4*k+3] = v.w;
            }
        }

        // ---- pre partials: 16 rows x local 16 cols
        float prep[16];
#pragma unroll
        for (int i = 0; i < 16; ++i)
            prep[i] = dot16(areg[2 * i], areg[2 * i + 1], hpr);

        // ---- reduce over the 16 nc-lanes entirely in VALU (DPP butterfly)
#pragma unroll
        for (int i = 0; i < 16; ++i) {
            prep[i] = dpp_add<0xB1>(prep[i]);    // xor1 (quad_perm 1,0,3,2)
            prep[i] = dpp_add<0x4E>(prep[i]);    // xor2 (quad_perm 2,3,0,1)
            prep[i] = dpp_add<0x141>(prep[i]);   // row_half_mirror
            prep[i] = dpp_add<0x128>(prep[i]);   // row_ror:8
        }

        // ---- wave max, then exact global max
        float mx = prep[0];
#pragma unroll
        for (int i = 1; i < 16; ++i) mx = fmaxf(mx, prep[i]);
        mx = fmaxf(mx, __shfl_xor(mx, 16));
        mx = fmaxf(mx, __shfl_xor(mx, 32));
        if (lane == 0) wred[w] = mx;
        __syncthreads();                                   // B1
        float gm = wred[0];
#pragma unroll
        for (int q = 1; q < 8; ++q) gm = fmaxf(gm, wred[q]);

        // ---- e in place of prep (saves 16 regs) + wave sum
        float ls = 0.f;
#pragma unroll
        for (int i = 0; i < 16; ++i) { prep[i] = __expf(prep[i] - gm); ls += prep[i]; }
        ls += __shfl_xor(ls, 16);
        ls += __shfl_xor(ls, 32);
        if (lane == 0) wsum[w] = ls;

        // ---- att partials over lane's rows for its 16 cols
        float attp[16];
#pragma unroll
        for (int j = 0; j < 16; ++j) attp[j] = 0.f;
#pragma unroll
        for (int i = 0; i < 16; ++i)
            axpy16(prep[i], areg[2 * i], areg[2 * i + 1], attp);
        // reduce over the 4 sr-groups
#pragma unroll
        for (int j = 0; j < 16; ++j) {
            attp[j] += __shfl_xor(attp[j], 16);
            attp[j] += __shfl_xor(attp[j], 32);
        }
        if (sr == 0) {
            float4* dst = (float4*)&att_part[w * 320 + nc * 20];
#pragma unroll
            for (int k = 0; k < 4; ++k)
                dst[k] = make_float4(attp[4*k], attp[4*k+1], attp[4*k+2], attp[4*k+3]);
        }
        __syncthreads();                                   // B2

        float l = wsum[0];
#pragma unroll
        for (int q = 1; q < 8; ++q) l += wsum[q];

        // ---- combine wave shards -> attsum (unnormalized)
        if (t < 256) {
            const int g = t >> 4, r = t & 15;
            float s = 0.f;
#pragma unroll
            for (int q = 0; q < 8; ++q) s += att_part[q * 320 + g * 20 + r];
            at_pad[g * 20 + r] = s;
        }
        __syncthreads();                                   // B3

        // ---- matvecs from L2 fp16: waves 4-7: Wc_ih.hp ; waves 0-3: Wc_hh.attsum
        {
            const uint2* Wp = W4T + (t >= 256 ? 0 : 64 * 256) + un;
            const float* xp = (t >= 256) ? hp_pad : at_pad;
            float a0 = 0.f, a1 = 0.f, a2 = 0.f, a3 = 0.f;
#pragma unroll
            for (int g = 0; g < 16; ++g) {
                uint2 w0 = Wp[(4 * g + 0) * 256];
                uint2 w1 = Wp[(4 * g + 1) * 256];
                uint2 w2 = Wp[(4 * g + 2) * 256];
                uint2 w3 = Wp[(4 * g + 3) * 256];
                const float4* xg = (const float4*)&xp[g * 20];
                float4 x0 = xg[0], x1 = xg[1], x2 = xg[2], x3 = xg[3];
                float2 f;
                f = h2f(w0.x); a0 = fmaf(f.x, x0.x, a0); a0 = fmaf(f.y, x0.y, a0);
                f = h2f(w0.y); a0 = fmaf(f.x, x0.z, a0); a0 = fmaf(f.y, x0.w, a0);
                f = h2f(w1.x); a1 = fmaf(f.x, x1.x, a1); a1 = fmaf(f.y, x1.y, a1);
                f = h2f(w1.y); a1 = fmaf(f.x, x1.z, a1); a1 = fmaf(f.y, x1.w, a1);
                f = h2f(w2.x); a2 = fmaf(f.x, x2.x, a2); a2 = fmaf(f.y, x2.y, a2);
                f = h2f(w2.y); a2 = fmaf(f.x, x2.z, a2); a2 = fmaf(f.y, x2.w, a2);
                f = h2f(w3.x); a3 = fmaf(f.x, x3.x, a3); a3 = fmaf(f.y, x3.y, a3);
                f = h2f(w3.y); a3 = fmaf(f.x, x3.z, a3); a3 = fmaf(f.y, x3.w, a3);
            }
            const float acc = (a0 + a1) + (a2 + a3);
            if (t >= 256) mvih[un] = acc;
            else          a_hh = acc;
        }
        __syncthreads();                                   // B4

        if (t < 256) {
            const float hn = tanhf(mvih[t] + a_hh / l + bcs);
            hp_pad[(t >> 4) * 20 + (t & 15)] = hn;
        }
        __syncthreads();                                   // B5
    }

    // ---- final FC
    float v = (t < 256) ? hp_pad[(t >> 4) * 20 + (t & 15)] * W_fc[un] : 0.f;
#pragma unroll
    for (int o = 32; o > 0; o >>= 1) v += __shfl_xor(v, o);
    if (lane == 0) wred[w] = v;
    __syncthreads();
    if (t == 0) {
        float s = b_fc[0];
#pragma unroll
        for (int q = 0; q < 8; ++q) s += wred[q];
        out[b] = s;
    }
}

// ===========================================================================
extern "C" void kernel_launch(void* const* d_in, const int* in_sizes, int n_in,
                              void* d_out, int out_size, void* d_ws, size_t ws_size,
                              hipStream_t stream) {
    const float* X     = (const float*)d_in[0];
    const float* W_ih  = (const float*)d_in[1];
    const float* W_hh  = (const float*)d_in[2];
    const float* b_ih  = (const float*)d_in[3];
    const float* b_hh  = (const float*)d_in[4];
    const float* Wc_ih = (const float*)d_in[5];
    const float* Wc_hh = (const float*)d_in[6];
    const float* bc_ih = (const float*)d_in[7];
    const float* bc_hh = (const float*)d_in[8];
    const float* W_fc  = (const float*)d_in[9];
    const float* b_fc  = (const float*)d_in[10];
    float* out = (float*)d_out;

    __half* A2  = (__half*)d_ws;                                    // 64 MiB
    uint2*  W4T = (uint2*)((char*)d_ws + (size_t)64 * 1024 * 1024); // 256 KiB

    pack_kernel<<<256, 64, 0, stream>>>(Wc_ih, Wc_hh, W4T);
    rnn_kernel<<<BATCH, 1024, 0, stream>>>(X, W_ih, W_hh, b_ih, b_hh, A2);
    attn_kernel<<<BATCH, 512, 0, stream>>>(A2, W4T, bc_ih, bc_hh,
                                           W_fc, b_fc, out);
}

// Round 9
// 10383.581 us; speedup vs baseline: 1.4972x; 1.4972x over previous
//
#include <hip/hip_runtime.h>
#include <hip/hip_fp16.h>
#include <math.h>

#define NSTEPS 512
#define BATCH  256
#define NIN    64
#define NN     256

__device__ __forceinline__ float2 h2f(uint32_t u) {
    __half2 h; *(uint32_t*)&h = u; return __half22float2(h);
}

// butterfly-add within 16-lane DPP row; CTRL: 0xB1=xor1, 0x4E=xor2,
// 0x141=row_half_mirror, 0x128=row_ror:8 -> full 16-lane sum in every lane
// (sequence validated end-to-end in R6, absmax 6.1e-5)
template<int CTRL>
__device__ __forceinline__ float dpp_add(float v) {
    int p = __builtin_amdgcn_update_dpp(0, __float_as_int(v), CTRL, 0xF, 0xF, true);
    return v + __int_as_float(p);
}

// ===========================================================================
// Phase 0: pack Wc_ih / Wc_hh transposed + k-quad-packed fp16:
//   W4T[(m*64 + kq)*256 + n] = half4{ Wc_m[n][4kq..4kq+3] }
// ===========================================================================
extern "C" __global__ void pack_kernel(const float* __restrict__ Wc_ih,
                                       const float* __restrict__ Wc_hh,
                                       uint2* __restrict__ W4T)
{
    const int n = blockIdx.x, t = threadIdx.x;
    {
        float4 v = ((const float4*)(Wc_ih + n * NN))[t];
        __half2 a = __floats2half2_rn(v.x, v.y);
        __half2 c = __floats2half2_rn(v.z, v.w);
        uint2 o; o.x = *(uint32_t*)&a; o.y = *(uint32_t*)&c;
        W4T[t * 256 + n] = o;
    }
    {
        float4 v = ((const float4*)(Wc_hh + n * NN))[t];
        __half2 a = __floats2half2_rn(v.x, v.y);
        __half2 c = __floats2half2_rn(v.z, v.w);
        uint2 o; o.x = *(uint32_t*)&a; o.y = *(uint32_t*)&c;
        W4T[(64 + t) * 256 + n] = o;
    }
}

// ===========================================================================
// Phase 1: tanh RNN. 1024 threads, (n = t&255, kq = t>>8). 80-reg weight
// arrays fit the 128-reg budget. Writes A2 (B, S, N) fp16.
// ===========================================================================
extern "C" __global__ void __launch_bounds__(1024, 1)
rnn_kernel(const float* __restrict__ X, const float* __restrict__ W_ih,
           const float* __restrict__ W_hh, const float* __restrict__ b_ih,
           const float* __restrict__ b_hh, __half* __restrict__ A2)
{
    const int b = blockIdx.x, t = threadIdx.x;
    const int n = t & 255, kq = t >> 8;

    __shared__ float h_lds[NN];
    __shared__ float x_lds[NIN];
    __shared__ float part[4 * NN];

    float wih[16];
#pragma unroll
    for (int j = 0; j < 16; ++j) wih[j] = W_ih[n * NIN + kq * 16 + j];
    float whh[64];
#pragma unroll
    for (int j = 0; j < 64; ++j) whh[j] = W_hh[n * NN + kq * 64 + j];
    const float bias = b_ih[n] + b_hh[n];

    float xr = (t < NIN) ? X[b * NIN + t] : 0.f;
    if (t < NN) h_lds[t] = 0.f;
    __syncthreads();

    __half2* Ab2 = (__half2*)(A2 + (size_t)b * NSTEPS * NN);

    for (int s = 0; s < NSTEPS; ++s) {
        if (t < NIN) x_lds[t] = xr;
        __syncthreads();
        if (t < NIN && s + 1 < NSTEPS) xr = X[((s + 1) * BATCH + b) * NIN + t];

        float a0 = 0.f, a1 = 0.f;
#pragma unroll
        for (int j = 0; j < 16; ++j) a0 = fmaf(wih[j], x_lds[kq * 16 + j], a0);
#pragma unroll
        for (int j = 0; j < 64; ++j) a1 = fmaf(whh[j], h_lds[kq * 64 + j], a1);
        part[kq * NN + n] = a0 + a1;
        __syncthreads();
        if (t < NN) {
            const float hn = tanhf(part[t] + part[NN + t] + part[2 * NN + t] +
                                   part[3 * NN + t] + bias);
            h_lds[t] = hn;
            const float hn1 = __shfl_down(hn, 1);
            if (!(t & 1)) Ab2[s * (NN / 2) + (t >> 1)] = __floats2half2_rn(hn, hn1);
        }
        __syncthreads();
    }
}

// ===========================================================================
// Phase 2 v4: REGISTER-RESIDENT A sized for the OBSERVED 128-VGPR cap.
// 1024 threads (16 waves). Lane (w=t>>6, sr=lane>>4, nc=lane&15) holds
// A rows w*32+sr*8..+7, cols nc*16..+15 as 16 uint4 (64 VGPRs).
// Per iteration:
//   pre: 8 local dot16 + DPP butterfly over nc (VALU only)
//   softmax: exact (global max across all 512), e in registers
//   att: local e*A, shuffle-reduce over sr, LDS combine over 16 waves
//   matvec: 4-way split (t>>8): {ih,hh} x {k 0..127, 128..255}
// 5 barriers/iter, zero global A traffic in loop, ~110 peak live VGPRs.
// ===========================================================================
__device__ __forceinline__ float dot16(uint4 wa, uint4 wb, const float* hpr) {
    float a = 0.f; float2 f;
    f = h2f(wa.x); a = fmaf(f.x, hpr[0],  a); a = fmaf(f.y, hpr[1],  a);
    f = h2f(wa.y); a = fmaf(f.x, hpr[2],  a); a = fmaf(f.y, hpr[3],  a);
    f = h2f(wa.z); a = fmaf(f.x, hpr[4],  a); a = fmaf(f.y, hpr[5],  a);
    f = h2f(wa.w); a = fmaf(f.x, hpr[6],  a); a = fmaf(f.y, hpr[7],  a);
    f = h2f(wb.x); a = fmaf(f.x, hpr[8],  a); a = fmaf(f.y, hpr[9],  a);
    f = h2f(wb.y); a = fmaf(f.x, hpr[10], a); a = fmaf(f.y, hpr[11], a);
    f = h2f(wb.z); a = fmaf(f.x, hpr[12], a); a = fmaf(f.y, hpr[13], a);
    f = h2f(wb.w); a = fmaf(f.x, hpr[14], a); a = fmaf(f.y, hpr[15], a);
    return a;
}

__device__ __forceinline__ void axpy16(float e, uint4 wa, uint4 wb, float* ap) {
    float2 f;
    f = h2f(wa.x); ap[0]  = fmaf(e, f.x, ap[0]);  ap[1]  = fmaf(e, f.y, ap[1]);
    f = h2f(wa.y); ap[2]  = fmaf(e, f.x, ap[2]);  ap[3]  = fmaf(e, f.y, ap[3]);
    f = h2f(wa.z); ap[4]  = fmaf(e, f.x, ap[4]);  ap[5]  = fmaf(e, f.y, ap[5]);
    f = h2f(wa.w); ap[6]  = fmaf(e, f.x, ap[6]);  ap[7]  = fmaf(e, f.y, ap[7]);
    f = h2f(wb.x); ap[8]  = fmaf(e, f.x, ap[8]);  ap[9]  = fmaf(e, f.y, ap[9]);
    f = h2f(wb.y); ap[10] = fmaf(e, f.x, ap[10]); ap[11] = fmaf(e, f.y, ap[11]);
    f = h2f(wb.z); ap[12] = fmaf(e, f.x, ap[12]); ap[13] = fmaf(e, f.y, ap[13]);
    f = h2f(wb.w); ap[14] = fmaf(e, f.x, ap[14]); ap[15] = fmaf(e, f.y, ap[15]);
}

extern "C" __global__ void __launch_bounds__(1024, 1)
attn_kernel(const __half* __restrict__ A2, const uint2* __restrict__ W4T,
            const float* __restrict__ bc_ih, const float* __restrict__ bc_hh,
            const float* __restrict__ W_fc, const float* __restrict__ b_fc,
            float* __restrict__ out)
{
    __shared__ float hp_pad[320];         // 16 groups x (16 data + 4 pad)
    __shared__ float at_pad[320];
    __shared__ float att_part[16 * 320];  // per-wave col partials
    __shared__ float wred[16];
    __shared__ float wsum[16];
    __shared__ float mv_part[1024];

    const int b    = blockIdx.x;
    const int t    = threadIdx.x;
    const int lane = t & 63;
    const int w    = t >> 6;              // 0..15
    const int sr   = lane >> 4;           // 0..3
    const int nc   = lane & 15;           // 0..15
    const int un   = t & 255;
    const int grp  = t >> 8;              // 0..3 matvec group
    const float bcs = bc_ih[un] + bc_hh[un];

    // ---- load A tile: rows w*32+sr*8+i (i<8), cols nc*16..+15 (16 uint4)
    uint4 areg[16];
    {
        const uint4* gA = (const uint4*)(A2 + (size_t)b * NSTEPS * NN);
        const int rbase = w * 32 + sr * 8;
#pragma unroll
        for (int i = 0; i < 8; ++i) {
            areg[2 * i]     = gA[(rbase + i) * 32 + nc * 2];
            areg[2 * i + 1] = gA[(rbase + i) * 32 + nc * 2 + 1];
        }
    }

    if (t < 256) hp_pad[(t >> 4) * 20 + (t & 15)] = 0.f;
    __syncthreads();

    for (int it = 0; it < NN; ++it) {
        // ---- hp col slice (16 floats; nc-indexed, sr-duplicated = broadcast)
        float hpr[16];
        {
            const float4* hq = (const float4*)&hp_pad[nc * 20];
#pragma unroll
            for (int k = 0; k < 4; ++k) {
                float4 v = hq[k];
                hpr[4*k] = v.x; hpr[4*k+1] = v.y; hpr[4*k+2] = v.z; hpr[4*k+3] = v.w;
            }
        }

        // ---- pre partials: 8 rows x local 16 cols, then DPP reduce over nc
        float prep[8];
#pragma unroll
        for (int i = 0; i < 8; ++i)
            prep[i] = dot16(areg[2 * i], areg[2 * i + 1], hpr);
#pragma unroll
        for (int i = 0; i < 8; ++i) {
            prep[i] = dpp_add<0xB1>(prep[i]);
            prep[i] = dpp_add<0x4E>(prep[i]);
            prep[i] = dpp_add<0x141>(prep[i]);
            prep[i] = dpp_add<0x128>(prep[i]);
        }

        // ---- wave max (32 rows), then exact global max over 16 waves
        float mx = prep[0];
#pragma unroll
        for (int i = 1; i < 8; ++i) mx = fmaxf(mx, prep[i]);
        mx = fmaxf(mx, __shfl_xor(mx, 16));
        mx = fmaxf(mx, __shfl_xor(mx, 32));
        if (lane == 0) wred[w] = mx;
        __syncthreads();                                   // B1
        float gm = wred[0];
#pragma unroll
        for (int q = 1; q < 16; ++q) gm = fmaxf(gm, wred[q]);

        // ---- e in place of prep + wave sum
        float ls = 0.f;
#pragma unroll
        for (int i = 0; i < 8; ++i) { prep[i] = __expf(prep[i] - gm); ls += prep[i]; }
        ls += __shfl_xor(ls, 16);
        ls += __shfl_xor(ls, 32);
        if (lane == 0) wsum[w] = ls;

        // ---- att partials: 16 cols over this lane's 8 rows; reduce over sr
        float attp[16];
#pragma unroll
        for (int j = 0; j < 16; ++j) attp[j] = 0.f;
#pragma unroll
        for (int i = 0; i < 8; ++i)
            axpy16(prep[i], areg[2 * i], areg[2 * i + 1], attp);
#pragma unroll
        for (int j = 0; j < 16; ++j) {
            attp[j] += __shfl_xor(attp[j], 16);
            attp[j] += __shfl_xor(attp[j], 32);
        }
        if (sr == 0) {
            float4* dst = (float4*)&att_part[w * 320 + nc * 20];
#pragma unroll
            for (int k = 0; k < 4; ++k)
                dst[k] = make_float4(attp[4*k], attp[4*k+1], attp[4*k+2], attp[4*k+3]);
        }
        __syncthreads();                                   // B2

        float l = wsum[0];
#pragma unroll
        for (int q = 1; q < 16; ++q) l += wsum[q];

        // ---- combine 16 wave shards -> attsum (unnormalized)
        if (t < 256) {
            const int g = t >> 4, r = t & 15;
            float s = 0.f;
#pragma unroll
            for (int q = 0; q < 16; ++q) s += att_part[q * 320 + g * 20 + r];
            at_pad[g * 20 + r] = s;
        }
        __syncthreads();                                   // B3

        // ---- matvec, 4-way split: grp 0/1 = Wc_ih.hp (k lo/hi),
        //      grp 2/3 = Wc_hh.attsum (k lo/hi). 128 MACs/thread from L2.
        {
            const uint2* Wp = W4T + ((grp >> 1) * 64 + (grp & 1) * 32) * 256 + un;
            const float* xp = (grp >= 2) ? at_pad : hp_pad;
            float a0 = 0.f, a1 = 0.f, a2 = 0.f, a3 = 0.f;
#pragma unroll
            for (int g = 0; g < 8; ++g) {
                uint2 w0 = Wp[(4 * g + 0) * 256];
                uint2 w1 = Wp[(4 * g + 1) * 256];
                uint2 w2 = Wp[(4 * g + 2) * 256];
                uint2 w3 = Wp[(4 * g + 3) * 256];
                const float4* xg = (const float4*)&xp[((grp & 1) * 8 + g) * 20];
                float4 x0 = xg[0], x1 = xg[1], x2 = xg[2], x3 = xg[3];
                float2 f;
                f = h2f(w0.x); a0 = fmaf(f.x, x0.x, a0); a0 = fmaf(f.y, x0.y, a0);
                f = h2f(w0.y); a0 = fmaf(f.x, x0.z, a0); a0 = fmaf(f.y, x0.w, a0);
                f = h2f(w1.x); a1 = fmaf(f.x, x1.x, a1); a1 = fmaf(f.y, x1.y, a1);
                f = h2f(w1.y); a1 = fmaf(f.x, x1.z, a1); a1 = fmaf(f.y, x1.w, a1);
                f = h2f(w2.x); a2 = fmaf(f.x, x2.x, a2); a2 = fmaf(f.y, x2.y, a2);
                f = h2f(w2.y); a2 = fmaf(f.x, x2.z, a2); a2 = fmaf(f.y, x2.w, a2);
                f = h2f(w3.x); a3 = fmaf(f.x, x3.x, a3); a3 = fmaf(f.y, x3.y, a3);
                f = h2f(w3.y); a3 = fmaf(f.x, x3.z, a3); a3 = fmaf(f.y, x3.w, a3);
            }
            mv_part[grp * 256 + un] = (a0 + a1) + (a2 + a3);
        }
        __syncthreads();                                   // B4

        if (t < 256) {
            const float hn = tanhf(mv_part[t] + mv_part[256 + t] +
                                   (mv_part[512 + t] + mv_part[768 + t]) / l + bcs);
            hp_pad[(t >> 4) * 20 + (t & 15)] = hn;
        }
        __syncthreads();                                   // B5
    }

    // ---- final FC (waves 0-3 hold t<256)
    float v = (t < 256) ? hp_pad[(t >> 4) * 20 + (t & 15)] * W_fc[un] : 0.f;
#pragma unroll
    for (int o = 32; o > 0; o >>= 1) v += __shfl_xor(v, o);
    if (t < 256 && lane == 0) wred[w] = v;
    __syncthreads();
    if (t == 0) {
        float s = b_fc[0];
#pragma unroll
        for (int q = 0; q < 4; ++q) s += wred[q];
        out[b] = s;
    }
}

// ===========================================================================
extern "C" void kernel_launch(void* const* d_in, const int* in_sizes, int n_in,
                              void* d_out, int out_size, void* d_ws, size_t ws_size,
                              hipStream_t stream) {
    const float* X     = (const float*)d_in[0];
    const float* W_ih  = (const float*)d_in[1];
    const float* W_hh  = (const float*)d_in[2];
    const float* b_ih  = (const float*)d_in[3];
    const float* b_hh  = (const float*)d_in[4];
    const float* Wc_ih = (const float*)d_in[5];
    const float* Wc_hh = (const float*)d_in[6];
    const float* bc_ih = (const float*)d_in[7];
    const float* bc_hh = (const float*)d_in[8];
    const float* W_fc  = (const float*)d_in[9];
    const float* b_fc  = (const float*)d_in[10];
    float* out = (float*)d_out;

    __half* A2  = (__half*)d_ws;                                    // 64 MiB
    uint2*  W4T = (uint2*)((char*)d_ws + (size_t)64 * 1024 * 1024); // 256 KiB

    pack_kernel<<<256, 64, 0, stream>>>(Wc_ih, Wc_hh, W4T);
    rnn_kernel<<<BATCH, 1024, 0, stream>>>(X, W_ih, W_hh, b_ih, b_hh, A2);
    attn_kernel<<<BATCH, 1024, 0, stream>>>(A2, W4T, bc_ih, bc_hh,
                                            W_fc, b_fc, out);
}